// Round 1
// baseline (239.770 us; speedup 1.0000x reference)
//
#include <hip/hip_runtime.h>
#include <math.h>

// LIF recurrence: v = v + (x_t - v)/tau; s = sigmoid(v - th); v *= (1 - s)
// x: [B=32, T=512, D=2048] fp32 -> spikes s, same shape.
// One thread per (b,d) chain, sequential over T (nonlinear recurrence).
// 65536 chains = 1024 waves = 1 wave/SIMD: zero TLP, latency hiding is pure
// ILP via outstanding VMEM ops.
//
// R2: the 2-deep (prefetch-distance-1) pipeline drains the memory queue every
// stage: 16 loads issued, ~600 cy compute, then a multi-thousand-cycle wait
// for the loads to land -> effective BW 1.19 TB/s (268 MB / 225.9 us) vs
// 6.6 TB/s achievable (fillBuffer dispatches in the same capture).
// Fix: 4-deep ring buffer, prefetch distance 3 -> 48 loads (12 KiB/wave)
// continuously in flight; 1024 waves x 12 KiB = 12 MB chip-wide, well past
// the ~2.4 MB bandwidth-delay product at 6.3 TB/s. 48 loads + 16 interleaved
// stores = 64 outstanding VMEM ops, right at the vmcnt=63 cap.
// Register cost: 4x16 = 64 buffer VGPRs — free at 1 wave/SIMD (512 VGPR
// budget). All buf[] indices are compile-time (outer loop unrolled by 4,
// inner loops fully) so the ring stays in registers, not scratch.

#define TAU_INV 0.5f
#define TH 1.0f

constexpr int BATCH = 32;
constexpr int TT = 512;
constexpr int DD = 2048;
constexpr int U = 16;            // time steps per pipeline stage
constexpr int NB = TT / U;       // 32 stages
constexpr int DEPTH = 4;         // ring depth: prefetch distance = DEPTH-1 = 3
static_assert((NB % DEPTH) == 0, "unroll-by-DEPTH needs NB % DEPTH == 0");

__global__ __launch_bounds__(256) void lif_kernel(const float* __restrict__ x,
                                                  float* __restrict__ out) {
    int tid = blockIdx.x * blockDim.x + threadIdx.x;  // [0, B*D)
    int b = tid >> 11;        // tid / D
    int d = tid & (DD - 1);   // tid % D
    const float* xp = x + (size_t)b * TT * DD + d;
    float* op = out + (size_t)b * TT * DD + d;

    float buf[DEPTH][U];

    // Prologue: fill ring slots 0..DEPTH-2 with stages 0..DEPTH-2
    // (48 loads issued back-to-back before any compute).
    #pragma unroll
    for (int st = 0; st < DEPTH - 1; ++st) {
        const float* xs = xp + (size_t)st * U * DD;
        #pragma unroll
        for (int i = 0; i < U; ++i)
            buf[st][i] = __builtin_nontemporal_load(xs + (size_t)i * DD);
    }

    float v = 0.0f;
    // unroll by DEPTH makes (blk & (DEPTH-1)) compile-time so the ring
    // stays in registers.
    #pragma unroll 4
    for (int blk = 0; blk < NB; ++blk) {
        const int cur = blk & (DEPTH - 1);

        // Prefetch stage blk+3 BEFORE computing stage blk: its loads only
        // need to land 3 compute-phases (~2-3k cycles) from now, so the
        // wave never sits on an empty memory queue.
        const int pf = blk + DEPTH - 1;
        if (pf < NB) {
            const int pslot = pf & (DEPTH - 1);
            const float* xn = xp + (size_t)pf * U * DD;
            #pragma unroll
            for (int i = 0; i < U; ++i)
                buf[pslot][i] = __builtin_nontemporal_load(xn + (size_t)i * DD);
        }

        // Compute stage blk (16 dependent LIF steps) + streamed stores.
        // Math is bit-identical to the verified 225.9us kernel.
        float* ob = op + (size_t)blk * U * DD;
        #pragma unroll
        for (int i = 0; i < U; ++i) {
            v = v + (buf[cur][i] - v) * TAU_INV;         // leak/integrate
            float s = 1.0f / (1.0f + __expf(TH - v));    // sigmoid(v - th)
            __builtin_nontemporal_store(s, ob + (size_t)i * DD);
            v = v * (1.0f - s);                           // soft reset
        }
    }
}

extern "C" void kernel_launch(void* const* d_in, const int* in_sizes, int n_in,
                              void* d_out, int out_size, void* d_ws, size_t ws_size,
                              hipStream_t stream) {
    const float* x = (const float*)d_in[0];
    float* out = (float*)d_out;
    const int threads = 256;
    const int total = BATCH * DD;                        // 65536 chains
    const int blocks = (total + threads - 1) / threads;  // 256
    lif_kernel<<<blocks, threads, 0, stream>>>(x, out);
}